// Round 4
// baseline (268.311 us; speedup 1.0000x reference)
//
#include <hip/hip_runtime.h>
#include <math.h>

#define D_DIM 32000
#define NV4   8000      // D_DIM / 4
#define BLOCK 1024
#define KMAX  8         // NV4 / BLOCK (rounded up)
#define RPB   16        // rows per block (persistent pipeline)
#define NBINS      3125 // 5^5 lattice cells of the n-section
#define NBINS_PAD  4096

// lattice over y = Xs - max(Xs), interval [-1, -(1/32000)^0.5]
#define BINW_F   3.182111456180002e-4f   // W0/3125
#define INVBW_F  3142.5681f              // 3125/W0

typedef float floatx4 __attribute__((ext_vector_type(4)));   // native vec for nontemporal store

// Raw barrier: drain LDS (lgkmcnt) only — prefetch global loads (vmcnt) stay
// in flight across it. __syncthreads() would emit s_waitcnt vmcnt(0) and kill
// the software pipeline. "memory" clobbers pin LDS ops on both sides.
__device__ __forceinline__ void barrier_lds() {
    asm volatile("s_waitcnt lgkmcnt(0)" ::: "memory");
    __builtin_amdgcn_s_barrier();
    asm volatile("" ::: "memory");
}

// ---- block-wide reduction helpers (16 waves of 64 lanes) ----

__device__ __forceinline__ float blockReduceMax(float v, float* s_tmp, int tid) {
    const int lane = tid & 63;
    const int wid  = tid >> 6;
#pragma unroll
    for (int o = 32; o > 0; o >>= 1) v = fmaxf(v, __shfl_xor(v, o));
    if (lane == 0) s_tmp[wid] = v;
    barrier_lds();
    if (tid < 16) {
        v = s_tmp[tid];
#pragma unroll
        for (int o = 8; o > 0; o >>= 1) v = fmaxf(v, __shfl_xor(v, o));
        if (tid == 0) s_tmp[0] = v;
    }
    barrier_lds();
    v = s_tmp[0];
    barrier_lds();   // s_tmp free for reuse
    return v;
}

__device__ __forceinline__ float4 blockReduceSum4(float4 a, float* s_tmp, int tid) {
    const int lane = tid & 63;
    const int wid  = tid >> 6;
#pragma unroll
    for (int o = 32; o > 0; o >>= 1) {
        a.x += __shfl_xor(a.x, o);
        a.y += __shfl_xor(a.y, o);
        a.z += __shfl_xor(a.z, o);
        a.w += __shfl_xor(a.w, o);
    }
    if (lane == 0) {
        s_tmp[wid * 4 + 0] = a.x; s_tmp[wid * 4 + 1] = a.y;
        s_tmp[wid * 4 + 2] = a.z; s_tmp[wid * 4 + 3] = a.w;
    }
    barrier_lds();
    if (tid < 16) {
        a.x = s_tmp[tid * 4 + 0]; a.y = s_tmp[tid * 4 + 1];
        a.z = s_tmp[tid * 4 + 2]; a.w = s_tmp[tid * 4 + 3];
#pragma unroll
        for (int o = 8; o > 0; o >>= 1) {
            a.x += __shfl_xor(a.x, o);
            a.y += __shfl_xor(a.y, o);
            a.z += __shfl_xor(a.z, o);
            a.w += __shfl_xor(a.w, o);
        }
        if (tid == 0) {
            s_tmp[0] = a.x; s_tmp[1] = a.y; s_tmp[2] = a.z; s_tmp[3] = a.w;
        }
    }
    barrier_lds();
    a.x = s_tmp[0]; a.y = s_tmp[1]; a.z = s_tmp[2]; a.w = s_tmp[3];
    barrier_lds();   // s_tmp free for reuse
    return a;
}

// ---- persistent kernel: 16 rows/block, double-buffered register pipeline ----

__global__ void __launch_bounds__(BLOCK, 4)
entmax_nsect_kernel(const float* __restrict__ X, float* __restrict__ out, int n_rows) {
    const int tid  = threadIdx.x;
    const int lane = tid & 63;
    const int wid  = tid >> 6;
    const int row0 = blockIdx.x * RPB;

    __shared__ float s_red[64];          // reduction scratch
    __shared__ float s_wv[48];           // 16 wave totals x 3 moments (scan stage)
    __shared__ float sC[NBINS_PAD];      // count  -> suffix count
    __shared__ float sS[NBINS_PAD];      // sum    -> suffix sum
    __shared__ float sQ[NBINS_PAD];      // sumsq  -> suffix sumsq

    float4 A[KMAX], B[KMAX];
#pragma unroll
    for (int k = 0; k < KMAX; ++k) {
        A[k] = make_float4(-INFINITY, -INFINITY, -INFINITY, -INFINITY);
        B[k] = A[k];
    }
    if (row0 < n_rows) {
        const float4* __restrict__ xr =
            reinterpret_cast<const float4*>(X + (size_t)row0 * D_DIM);
#pragma unroll
        for (int k = 0; k < KMAX; ++k) {
            const int j = tid + k * BLOCK;
            if (j < NV4) A[k] = xr[j];
        }
    }

    // per-row body: consume `cur` (raw values), prefetch row r+1 into `nxt`
    auto process = [&](float4 (&cur)[KMAX], float4 (&nxt)[KMAX], int r) {
        const int row = row0 + r;
        if (row >= n_rows) return;          // block-uniform

        // prefetch next row (vmcnt stays outstanding through all barriers)
        if (r + 1 < RPB && row + 1 < n_rows) {
            const float4* __restrict__ nrow =
                reinterpret_cast<const float4*>(X + (size_t)(row + 1) * D_DIM);
#pragma unroll
            for (int k = 0; k < KMAX; ++k) {
                const int j = tid + k * BLOCK;
                if (j < NV4) nxt[k] = nrow[j];
            }
        }

        // Phase 1: block max (on raw values; scale by alpha-1=0.5 afterwards)
        float mx = -INFINITY;
#pragma unroll
        for (int k = 0; k < KMAX; ++k)
            mx = fmaxf(mx, fmaxf(fmaxf(cur[k].x, cur[k].y), fmaxf(cur[k].z, cur[k].w)));
        const float maxXs = 0.5f * blockReduceMax(mx, s_red, tid);

        // zero histogram planes (prev row's table reads are behind the reduce barriers)
        {
            const float4 z4 = make_float4(0.f, 0.f, 0.f, 0.f);
            reinterpret_cast<float4*>(sC)[tid] = z4;
            reinterpret_cast<float4*>(sS)[tid] = z4;
            reinterpret_cast<float4*>(sQ)[tid] = z4;
        }
        barrier_lds();

        // Phase 2: moment histogram over y = 0.5*raw - max, candidates y > -1
#pragma unroll
        for (int k = 0; k < KMAX; ++k) {
            const float ys[4] = { fmaf(cur[k].x, 0.5f, -maxXs),
                                  fmaf(cur[k].y, 0.5f, -maxXs),
                                  fmaf(cur[k].z, 0.5f, -maxXs),
                                  fmaf(cur[k].w, 0.5f, -maxXs) };
#pragma unroll
            for (int c = 0; c < 4; ++c) {
                const float y = ys[c];
                if (y > -1.0f) {
                    const int b = (int)fminf((y + 1.0f) * INVBW_F, 3124.0f);
                    atomicAdd(&sC[b], 1.0f);
                    atomicAdd(&sS[b], y);
                    atomicAdd(&sQ[b], y * y);
                }
            }
        }
        barrier_lds();

        // Phase 3: in-place suffix scan -> SUF[k] = sum over bins >= k
        float4 c4 = reinterpret_cast<const float4*>(sC)[tid];
        float4 s4 = reinterpret_cast<const float4*>(sS)[tid];
        float4 q4 = reinterpret_cast<const float4*>(sQ)[tid];
        const float cT = c4.x + c4.y + c4.z + c4.w;
        const float sT = s4.x + s4.y + s4.z + s4.w;
        const float qT = q4.x + q4.y + q4.z + q4.w;
        float ci = cT, si = sT, qi = qT;
#pragma unroll
        for (int o = 1; o < 64; o <<= 1) {
            float a = __shfl_down(ci, o);
            float b = __shfl_down(si, o);
            float c = __shfl_down(qi, o);
            if (lane + o < 64) { ci += a; si += b; qi += c; }
        }
        if (lane == 0) { s_wv[wid] = ci; s_wv[16 + wid] = si; s_wv[32 + wid] = qi; }
        barrier_lds();
        if (tid < 16) {
            float wc = s_wv[tid], ws = s_wv[16 + tid], wq = s_wv[32 + tid];
            const float oc = wc, os = ws, oq = wq;
#pragma unroll
            for (int o = 1; o < 16; o <<= 1) {
                float a = __shfl_down(wc, o);
                float b = __shfl_down(ws, o);
                float c = __shfl_down(wq, o);
                if (tid + o < 16) { wc += a; ws += b; wq += c; }
            }
            s_wv[tid] = wc - oc; s_wv[16 + tid] = ws - os; s_wv[32 + tid] = wq - oq;
        }
        barrier_lds();
        {
            const float ac = s_wv[wid] + (ci - cT);
            const float as = s_wv[16 + wid] + (si - sT);
            const float aq = s_wv[32 + wid] + (qi - qT);
            float4 co, so, qo;
            co.w = ac + c4.w; co.z = co.w + c4.z; co.y = co.z + c4.y; co.x = co.y + c4.x;
            so.w = as + s4.w; so.z = so.w + s4.z; so.y = so.z + s4.y; so.x = so.y + s4.x;
            qo.w = aq + q4.w; qo.z = qo.w + q4.z; qo.y = qo.z + q4.y; qo.x = qo.y + q4.x;
            reinterpret_cast<float4*>(sC)[tid] = co;
            reinterpret_cast<float4*>(sS)[tid] = so;
            reinterpret_cast<float4*>(sQ)[tid] = qo;
        }
        barrier_lds();

        // Phase 4: n-section via table lookups (no barriers, all threads redundant)
        int lo_idx = 0;
        int w = 625;
#pragma unroll
        for (int it = 0; it < 5; ++it) {
            int nl = lo_idx;
#pragma unroll
            for (int j = 1; j <= 4; ++j) {
                const int k = lo_idx + j * w;
                const float t  = fmaf((float)k, BINW_F, -1.0f);
                const float Ck = sC[k];
                const float Sk = sS[k];
                const float Qk = sQ[k];
                const float ssum = fmaf(t, fmaf(t, Ck, -2.0f * Sk), Qk);
                if (ssum >= 1.0f) nl = k;
            }
            lo_idx = nl;
            w /= 5;
        }
        const float tauY = fmaf((float)lo_idx + 0.5f, BINW_F, -1.0f);
        const float tau  = maxXs + tauY;

        // Phase 5: exact normalizer from registers (one reduction)
        float4 zacc = make_float4(0.f, 0.f, 0.f, 0.f);
#pragma unroll
        for (int k = 0; k < KMAX; ++k) {
            float d;
            d = fmaxf(fmaf(cur[k].x, 0.5f, -tau), 0.f); zacc.x = fmaf(d, d, zacc.x);
            d = fmaxf(fmaf(cur[k].y, 0.5f, -tau), 0.f); zacc.y = fmaf(d, d, zacc.y);
            d = fmaxf(fmaf(cur[k].z, 0.5f, -tau), 0.f); zacc.z = fmaf(d, d, zacc.z);
            d = fmaxf(fmaf(cur[k].w, 0.5f, -tau), 0.f); zacc.w = fmaf(d, d, zacc.w);
        }
        zacc = blockReduceSum4(zacc, s_red, tid);
        const float invZ = 1.0f / (zacc.x + zacc.y + zacc.z + zacc.w);

        // Phase 6: write output (non-temporal; out is never re-read)
        floatx4* __restrict__ orow = reinterpret_cast<floatx4*>(out + (size_t)row * D_DIM);
#pragma unroll
        for (int k = 0; k < KMAX; ++k) {
            const int j = tid + k * BLOCK;
            if (j < NV4) {
                float d;
                floatx4 p;
                d = fmaxf(fmaf(cur[k].x, 0.5f, -tau), 0.f); p.x = d * d * invZ;
                d = fmaxf(fmaf(cur[k].y, 0.5f, -tau), 0.f); p.y = d * d * invZ;
                d = fmaxf(fmaf(cur[k].z, 0.5f, -tau), 0.f); p.z = d * d * invZ;
                d = fmaxf(fmaf(cur[k].w, 0.5f, -tau), 0.f); p.w = d * d * invZ;
                __builtin_nontemporal_store(p, &orow[j]);
            }
        }
    };

    // 2-step unrolled swap: all register-array indices compile-time (rule #20)
#pragma unroll 1
    for (int rr = 0; rr < RPB; rr += 2) {
        process(A, B, rr);
        process(B, A, rr + 1);
    }
}

extern "C" void kernel_launch(void* const* d_in, const int* in_sizes, int n_in,
                              void* d_out, int out_size, void* d_ws, size_t ws_size,
                              hipStream_t stream) {
    const float* X = (const float*)d_in[0];
    float* out     = (float*)d_out;
    const int n_rows = in_sizes[0] / D_DIM;            // 4096
    const int grid   = (n_rows + RPB - 1) / RPB;       // 256 blocks -> 1 per CU
    entmax_nsect_kernel<<<dim3(grid), dim3(BLOCK), 0, stream>>>(X, out, n_rows);
}

// Round 5
// 259.427 us; speedup vs baseline: 1.0342x; 1.0342x over previous
//
#include <hip/hip_runtime.h>
#include <math.h>

#define D_DIM 32000
#define NV4   8000      // D_DIM / 4
#define BLOCK 1024
#define KMAX  8         // NV4 / BLOCK (rounded up)
#define NBINS 3125      // 5^5 lattice cells of the n-section
#define NPAD  4096

// lattice over y = Xs - max(Xs), interval [-1, -(1/32000)^0.5]
#define BINW_F   3.182111456180002e-4f   // W0/3125
#define INVBW_F  3142.5681f              // 3125/W0

typedef float floatx4 __attribute__((ext_vector_type(4)));   // native vec for nontemporal store

// ---- one block per row, row in registers, histogram n-section, 5 barriers ----

__global__ void __launch_bounds__(BLOCK, 8)
entmax_nsect_kernel(const float* __restrict__ X, float* __restrict__ out, int n_rows) {
    const int row = blockIdx.x;
    if (row >= n_rows) return;
    const int tid  = threadIdx.x;
    const int lane = tid & 63;
    const int wid  = tid >> 6;

    __shared__ __align__(16) float sC[NPAD];      // count  -> suffix count
    __shared__ __align__(16) float sS[NPAD];      // sum    -> suffix sum
    __shared__ __align__(16) float sQ[NPAD];      // sumsq  -> suffix sumsq
    __shared__ __align__(16) float s_wmax[16];    // per-wave max partials
    __shared__ __align__(16) float s_wv[48];      // 16 wave totals x 3 moments

    const float4* __restrict__ xrow = reinterpret_cast<const float4*>(X + (size_t)row * D_DIM);
    floatx4* __restrict__ orow      = reinterpret_cast<floatx4*>(out + (size_t)row * D_DIM);

    // Phase 1: load row (raw), per-thread max, wave shfl-reduce, zero LDS planes.
    float4 v[KMAX];
    float mx = -INFINITY;
#pragma unroll
    for (int k = 0; k < KMAX; ++k) {
        const int j = tid + k * BLOCK;
        if (j < NV4) v[k] = xrow[j];
        else         v[k] = make_float4(-INFINITY, -INFINITY, -INFINITY, -INFINITY);
    }
    {   // zero histogram planes while loads are in flight
        const float4 z4 = make_float4(0.f, 0.f, 0.f, 0.f);
        reinterpret_cast<float4*>(sC)[tid] = z4;
        reinterpret_cast<float4*>(sS)[tid] = z4;
        reinterpret_cast<float4*>(sQ)[tid] = z4;
    }
#pragma unroll
    for (int k = 0; k < KMAX; ++k)
        mx = fmaxf(mx, fmaxf(fmaxf(v[k].x, v[k].y), fmaxf(v[k].z, v[k].w)));
#pragma unroll
    for (int o = 32; o > 0; o >>= 1) mx = fmaxf(mx, __shfl_xor(mx, o));
    if (lane == 0) s_wmax[wid] = mx;
    __syncthreads();                                   // B1

    // redundant block max from 16 partials (LDS broadcast reads)
    float m0;
    {
        const float4 a = reinterpret_cast<const float4*>(s_wmax)[0];
        const float4 b = reinterpret_cast<const float4*>(s_wmax)[1];
        const float4 c = reinterpret_cast<const float4*>(s_wmax)[2];
        const float4 d = reinterpret_cast<const float4*>(s_wmax)[3];
        m0 = fmaxf(fmaxf(fmaxf(a.x, a.y), fmaxf(a.z, a.w)),
                   fmaxf(fmaxf(fmaxf(b.x, b.y), fmaxf(b.z, b.w)),
                         fmaxf(fmaxf(fmaxf(c.x, c.y), fmaxf(c.z, c.w)),
                               fmaxf(fmaxf(d.x, d.y), fmaxf(d.z, d.w)))));
    }
    const float maxXs = 0.5f * m0;                     // scale by alpha-1 = 0.5

    // Phase 2: moment histogram over y = 0.5*raw - max, candidates y > -1.
#pragma unroll
    for (int k = 0; k < KMAX; ++k) {
        const float ys[4] = { fmaf(v[k].x, 0.5f, -maxXs),
                              fmaf(v[k].y, 0.5f, -maxXs),
                              fmaf(v[k].z, 0.5f, -maxXs),
                              fmaf(v[k].w, 0.5f, -maxXs) };
#pragma unroll
        for (int c = 0; c < 4; ++c) {
            const float y = ys[c];
            if (y > -1.0f) {
                const int b = (int)fminf(fmaf(y, INVBW_F, INVBW_F), 3124.0f);
                atomicAdd(&sC[b], 1.0f);
                atomicAdd(&sS[b], y);
                atomicAdd(&sQ[b], y * y);
            }
        }
    }
    __syncthreads();                                   // B2

    // Phase 3: suffix scan -> SUF[k] = sum over bins >= k, per moment.
    float4 c4 = reinterpret_cast<const float4*>(sC)[tid];
    float4 s4 = reinterpret_cast<const float4*>(sS)[tid];
    float4 q4 = reinterpret_cast<const float4*>(sQ)[tid];
    const float cT = c4.x + c4.y + c4.z + c4.w;
    const float sT = s4.x + s4.y + s4.z + s4.w;
    const float qT = q4.x + q4.y + q4.z + q4.w;
    float ci = cT, si = sT, qi = qT;                   // inclusive suffix within wave
#pragma unroll
    for (int o = 1; o < 64; o <<= 1) {
        float a = __shfl_down(ci, o);
        float b = __shfl_down(si, o);
        float c = __shfl_down(qi, o);
        if (lane + o < 64) { ci += a; si += b; qi += c; }
    }
    if (lane == 0) { s_wv[wid] = ci; s_wv[16 + wid] = si; s_wv[32 + wid] = qi; }
    __syncthreads();                                   // B3
    if (tid < 16) {
        float wc = s_wv[tid], ws = s_wv[16 + tid], wq = s_wv[32 + tid];
        const float oc = wc, os = ws, oq = wq;
#pragma unroll
        for (int o = 1; o < 16; o <<= 1) {
            float a = __shfl_down(wc, o);
            float b = __shfl_down(ws, o);
            float c = __shfl_down(wq, o);
            if (tid + o < 16) { wc += a; ws += b; wq += c; }
        }
        // exclusive suffix from waves above this one
        s_wv[tid] = wc - oc; s_wv[16 + tid] = ws - os; s_wv[32 + tid] = wq - oq;
    }
    __syncthreads();                                   // B4
    {
        const float ac = s_wv[wid] + (ci - cT);
        const float as = s_wv[16 + wid] + (si - sT);
        const float aq = s_wv[32 + wid] + (qi - qT);
        float4 co, so, qo;
        co.w = ac + c4.w; co.z = co.w + c4.z; co.y = co.z + c4.y; co.x = co.y + c4.x;
        so.w = as + s4.w; so.z = so.w + s4.z; so.y = so.z + s4.y; so.x = so.y + s4.x;
        qo.w = aq + q4.w; qo.z = qo.w + q4.z; qo.y = qo.z + q4.y; qo.x = qo.y + q4.x;
        reinterpret_cast<float4*>(sC)[tid] = co;
        reinterpret_cast<float4*>(sS)[tid] = so;
        reinterpret_cast<float4*>(sQ)[tid] = qo;
    }
    __syncthreads();                                   // B5

    // Phase 4: n-section via table lookups (no barriers, all threads redundant).
    // f(t) >= 0  <=>  Q - 2 t S + t^2 C >= 1  at lattice boundary t_k = -1 + k*binw.
    int lo_idx = 0;
    int w = 625;
#pragma unroll
    for (int it = 0; it < 5; ++it) {
        int nl = lo_idx;
#pragma unroll
        for (int j = 1; j <= 4; ++j) {
            const int k = lo_idx + j * w;
            const float t  = fmaf((float)k, BINW_F, -1.0f);
            const float Ck = sC[k];
            const float Sk = sS[k];
            const float Qk = sQ[k];
            const float ssum = fmaf(t, fmaf(t, Ck, -2.0f * Sk), Qk);
            if (ssum >= 1.0f) nl = k;
        }
        lo_idx = nl;
        w /= 5;
    }
    const float tauY = fmaf((float)lo_idx + 0.5f, BINW_F, -1.0f);
    const float tau  = maxXs + tauY;

    // Phase 5: Z from the suffix moments at the final bin (exact to ~1e-6; Z ~= 1).
    const float Ck = sC[lo_idx];
    const float Sk = sS[lo_idx];
    const float Qk = sQ[lo_idx];
    const float Z  = fmaf(tauY, fmaf(tauY, Ck, -2.0f * Sk), Qk);
    const float invZ = 1.0f / Z;

    // Phase 6: write output from registers (non-temporal; out is never re-read).
#pragma unroll
    for (int k = 0; k < KMAX; ++k) {
        const int j = tid + k * BLOCK;
        if (j < NV4) {
            float d;
            floatx4 p;
            d = fmaxf(fmaf(v[k].x, 0.5f, -tau), 0.f); p.x = d * d * invZ;
            d = fmaxf(fmaf(v[k].y, 0.5f, -tau), 0.f); p.y = d * d * invZ;
            d = fmaxf(fmaf(v[k].z, 0.5f, -tau), 0.f); p.z = d * d * invZ;
            d = fmaxf(fmaf(v[k].w, 0.5f, -tau), 0.f); p.w = d * d * invZ;
            __builtin_nontemporal_store(p, &orow[j]);
        }
    }
}

extern "C" void kernel_launch(void* const* d_in, const int* in_sizes, int n_in,
                              void* d_out, int out_size, void* d_ws, size_t ws_size,
                              hipStream_t stream) {
    const float* X = (const float*)d_in[0];
    float* out     = (float*)d_out;
    const int n_rows = in_sizes[0] / D_DIM;   // 4096
    entmax_nsect_kernel<<<dim3(n_rows), dim3(BLOCK), 0, stream>>>(X, out, n_rows);
}

// Round 6
// 204.428 us; speedup vs baseline: 1.3125x; 1.2690x over previous
//
#include <hip/hip_runtime.h>
#include <math.h>

#define D_DIM 32000
#define NV4   8000      // D_DIM / 4
#define BLOCK 256
#define KMAX  32        // ceil(NV4 / BLOCK)
#define NBINS 256

// lattice over y = Xs - max(Xs), interval [-1, -(1/32000)^0.5], W0 = 0.9944098300562505
#define BINW_F   3.8844134767822285e-3f  // W0/256
#define INVBW_F  257.43893f              // 256/W0

typedef float floatx4 __attribute__((ext_vector_type(4)));   // native vec for nontemporal store

// One block per row; row truly register-resident (asm-pinned); 256-bin moment
// histogram + suffix scan + binary search + exact quadratic solve for tau.
// 3 blocks/CU (VGPR-capped) give cross-row phase diversity for HBM overlap.

__global__ void __launch_bounds__(BLOCK, 3)
entmax_nsect_kernel(const float* __restrict__ X, float* __restrict__ out, int n_rows) {
    const int row = blockIdx.x;
    if (row >= n_rows) return;
    const int tid  = threadIdx.x;
    const int lane = tid & 63;
    const int wid  = tid >> 6;

    __shared__ __align__(16) float sC[NBINS];   // count  -> suffix count
    __shared__ __align__(16) float sS[NBINS];   // sum    -> suffix sum
    __shared__ __align__(16) float sQ[NBINS];   // sumsq  -> suffix sumsq
    __shared__ float s_wmax[4];                 // per-wave max partials

    const float4* __restrict__ xrow = reinterpret_cast<const float4*>(X + (size_t)row * D_DIM);
    floatx4* __restrict__ orow      = reinterpret_cast<floatx4*>(out + (size_t)row * D_DIM);

    // Phase 1: load row into registers (raw values).
    float4 v[KMAX];
#pragma unroll
    for (int k = 0; k < KMAX; ++k) {
        const int j = tid + k * BLOCK;
        if (j < NV4) v[k] = xrow[j];
        else         v[k] = make_float4(-INFINITY, -INFINITY, -INFINITY, -INFINITY);
    }
    // Pin: make values asm-opaque so the compiler cannot rematerialize them by
    // re-loading from global (the round-1..5 kernels silently did 3x reloads;
    // VGPR_Count=44 with a 32-reg row proved the row was never resident).
#pragma unroll
    for (int k = 0; k < KMAX; ++k)
        asm volatile("" : "+v"(v[k].x), "+v"(v[k].y), "+v"(v[k].z), "+v"(v[k].w));

    // zero histogram planes (256 threads, 1 element each)
    sC[tid] = 0.0f; sS[tid] = 0.0f; sQ[tid] = 0.0f;

    // per-thread + wave max
    float mx = -INFINITY;
#pragma unroll
    for (int k = 0; k < KMAX; ++k)
        mx = fmaxf(mx, fmaxf(fmaxf(v[k].x, v[k].y), fmaxf(v[k].z, v[k].w)));
#pragma unroll
    for (int o = 32; o > 0; o >>= 1) mx = fmaxf(mx, __shfl_xor(mx, o));
    if (lane == 0) s_wmax[wid] = mx;
    __syncthreads();                                   // B1

    const float m0 = fmaxf(fmaxf(s_wmax[0], s_wmax[1]), fmaxf(s_wmax[2], s_wmax[3]));
    const float maxXs = 0.5f * m0;                     // scale by alpha-1 = 0.5 (exact)

    // Phase 2: moment histogram over y = 0.5*raw - maxXs, candidates y > -1.
    // Bin index is quantized; accumulated moments use exact y values, so the
    // suffix moments at bin boundaries are EXACT sums over {y >= t_k}.
#pragma unroll
    for (int k = 0; k < KMAX; ++k) {
        const float ys[4] = { fmaf(v[k].x, 0.5f, -maxXs),
                              fmaf(v[k].y, 0.5f, -maxXs),
                              fmaf(v[k].z, 0.5f, -maxXs),
                              fmaf(v[k].w, 0.5f, -maxXs) };
#pragma unroll
        for (int c = 0; c < 4; ++c) {
            const float y = ys[c];
            if (y > -1.0f) {
                const int b = (int)fminf((y + 1.0f) * INVBW_F, 255.0f);
                atomicAdd(&sC[b], 1.0f);
                atomicAdd(&sS[b], y);
                atomicAdd(&sQ[b], y * y);
            }
        }
    }
    __syncthreads();                                   // B2

    // Phase 3: suffix scan (sum over bins >= k), one wave per moment plane.
    if (wid < 3) {
        float* plane = (wid == 0) ? sC : (wid == 1) ? sS : sQ;
        const float4 f = reinterpret_cast<const float4*>(plane)[lane];
        const float t3 = f.w;
        const float t2 = f.z + t3;
        const float t1 = f.y + t2;
        const float t0 = f.x + t1;
        float inc = t0;                                // inclusive suffix of lane totals
#pragma unroll
        for (int o = 1; o < 64; o <<= 1) {
            const float u = __shfl_down(inc, o);
            if (lane + o < 64) inc += u;
        }
        const float above = inc - t0;                  // exclusive suffix from higher lanes
        float4 o4;
        o4.x = t0 + above; o4.y = t1 + above; o4.z = t2 + above; o4.w = t3 + above;
        reinterpret_cast<float4*>(plane)[lane] = o4;
    }
    __syncthreads();                                   // B3

    // Phase 4: binary search for the bin containing the root of
    // f(t) = Q - 2tS + t^2 C = 1 (monotone decreasing; f(t_0) >= 1 always since
    // the max element contributes (0-(-1))^2 = 1). All threads redundant.
    int klo = 0, khi = 256;
#pragma unroll
    for (int it = 0; it < 8; ++it) {
        const int mid = (klo + khi) >> 1;
        const float t  = fmaf((float)mid, BINW_F, -1.0f);
        const float fm = fmaf(t, fmaf(t, sC[mid], -2.0f * sS[mid]), sQ[mid]);
        if (fm >= 1.0f) klo = mid; else khi = mid;
    }
    // Exact root within the bin: C*t^2 - 2*S*t + (Q-1) = 0, smaller root
    // (f decreasing there). Z = Q - 2 tau S + tau^2 C = 1 by construction,
    // so no normalization pass is needed.
    const float C = sC[klo], S = sS[klo], Q = sQ[klo];
    const float disc = fmaxf(fmaf(S, S, -C * (Q - 1.0f)), 0.0f);
    float tauY = (S - sqrtf(disc)) / C;                // C >= 1 (max element in every suffix)
    tauY = fminf(fmaxf(tauY, -1.0f), 0.0f);
    const float tau = maxXs + tauY;

    // Phase 5: write output from registers (non-temporal; out never re-read).
#pragma unroll
    for (int k = 0; k < KMAX; ++k) {
        const int j = tid + k * BLOCK;
        if (j < NV4) {
            float d;
            floatx4 p;
            d = fmaxf(fmaf(v[k].x, 0.5f, -tau), 0.f); p.x = d * d;
            d = fmaxf(fmaf(v[k].y, 0.5f, -tau), 0.f); p.y = d * d;
            d = fmaxf(fmaf(v[k].z, 0.5f, -tau), 0.f); p.z = d * d;
            d = fmaxf(fmaf(v[k].w, 0.5f, -tau), 0.f); p.w = d * d;
            __builtin_nontemporal_store(p, &orow[j]);
        }
    }
}

extern "C" void kernel_launch(void* const* d_in, const int* in_sizes, int n_in,
                              void* d_out, int out_size, void* d_ws, size_t ws_size,
                              hipStream_t stream) {
    const float* X = (const float*)d_in[0];
    float* out     = (float*)d_out;
    const int n_rows = in_sizes[0] / D_DIM;   // 4096
    entmax_nsect_kernel<<<dim3(n_rows), dim3(BLOCK), 0, stream>>>(X, out, n_rows);
}